// Round 8
// baseline (176.407 us; speedup 1.0000x reference)
//
#include <hip/hip_runtime.h>

typedef unsigned int uint;
typedef unsigned short ushort;
typedef unsigned char uchar;
typedef __attribute__((ext_vector_type(4))) float f32x4;
typedef __attribute__((ext_vector_type(4))) uint u32x4;
typedef __attribute__((ext_vector_type(2))) uint u32x2;

#define NNODES 100000
#define NPAD   100032
#define NEDGES 1600000
#define FD 128
#define BM 64

__device__ __forceinline__ uint cvt_pk_bf16(float lo, float hi) {
    uint r;
    asm("v_cvt_pk_bf16_f32 %0, %1, %2" : "=v"(r) : "v"(lo), "v"(hi));
    return r;
}
__device__ __forceinline__ int swz(int row, int k) {
    return (row * 256 + k * 2) ^ ((row & 7) << 4);
}

// ---------------------------------------------------------------------------
// prep: blocks 0-15 build Wt (bf16(W^T), pre-swizzled); blocks 16+ build
// row_ptr[r] = lower_bound(edge_row, r).
// ---------------------------------------------------------------------------
__global__ __launch_bounds__(256) void prep(const float* __restrict__ W,
                                            ushort* __restrict__ Wt,
                                            const int* __restrict__ rows,
                                            int* __restrict__ ptr) {
    const int bid = blockIdx.x;
    if (bid < 16) {
        const int sid = bid * 256 + threadIdx.x;   // 4096 slots
        const int n = sid & 127, k0 = (sid >> 7) * 4;
        const float w0 = W[(k0 + 0) * FD + n];
        const float w1 = W[(k0 + 1) * FD + n];
        const float w2 = W[(k0 + 2) * FD + n];
        const float w3 = W[(k0 + 3) * FD + n];
        u32x2 p;
        p.x = cvt_pk_bf16(w0, w1);
        p.y = cvt_pk_bf16(w2, w3);
        *(u32x2*)((char*)Wt + swz(n, k0)) = p;
    } else {
        const int r = (bid - 16) * 256 + threadIdx.x;
        if (r > NNODES) return;
        int lo = 0, hi = NEDGES;
        while (lo < hi) {
            const int mid = (lo + hi) >> 1;
            const bool lt = rows[mid] < r;
            lo = lt ? mid + 1 : lo;
            hi = lt ? hi : mid;
        }
        ptr[r] = lo;
    }
}

// ---------------------------------------------------------------------------
// GEMM: S = X @ W via bf16 MFMA + per-row symmetric int8 quant (biased u8).
// ---------------------------------------------------------------------------
__global__ __launch_bounds__(256) void gemm_mfma_q8(const float* __restrict__ X,
                                                    const ushort* __restrict__ Wt,
                                                    uchar* __restrict__ S8,
                                                    float* __restrict__ scale) {
    __shared__ ushort As[BM * FD];   // 16 KB, swizzled; reused as u8 in epilogue
    __shared__ ushort Bs[FD * FD];   // 32 KB, swizzled
    const int tid = threadIdx.x;
    const int row0 = blockIdx.x * BM;

    #pragma unroll
    for (int it = 0; it < 8; ++it) {
        const int idx = tid + it * 256;
        const int r = idx >> 5, k0 = (idx & 31) * 4;
        const int grow = min(row0 + r, NNODES - 1);
        const float4 g = *(const float4*)&X[grow * FD + k0];
        u32x2 p;
        p.x = cvt_pk_bf16(g.x, g.y);
        p.y = cvt_pk_bf16(g.z, g.w);
        *(u32x2*)((char*)As + swz(r, k0)) = p;
    }
    #pragma unroll
    for (int it = 0; it < 8; ++it) {
        const int b = (tid + it * 256) * 16;
        *(u32x4*)((char*)Bs + b) = *(const u32x4*)((const char*)Wt + b);
    }
    __syncthreads();

    const int lane = tid & 63, wv = tid >> 6;
    const int l15 = lane & 15, kg = lane >> 4;
    const int arow = wv * 16 + l15;

    f32x4 acc[8];
    #pragma unroll
    for (int i = 0; i < 8; ++i) acc[i] = (f32x4)0.f;

    #pragma unroll
    for (int ks = 0; ks < 4; ++ks) {
        const int k0 = ks * 32 + kg * 8;
        const u32x4 a = *(const u32x4*)((const char*)As + swz(arow, k0));
        #pragma unroll
        for (int nf = 0; nf < 8; ++nf) {
            const u32x4 b = *(const u32x4*)((const char*)Bs + swz(nf * 16 + l15, k0));
            asm volatile("v_mfma_f32_16x16x32_bf16 %0, %1, %2, %0"
                         : "+v"(acc[nf]) : "v"(a), "v"(b));
        }
    }
    asm volatile("s_nop 7\ns_nop 7\ns_nop 7");

    __syncthreads();
    uchar* As8 = (uchar*)As;

    #pragma unroll
    for (int r = 0; r < 4; ++r) {
        float m = 0.f;
        #pragma unroll
        for (int nf = 0; nf < 8; ++nf) m = fmaxf(m, fabsf(acc[nf][r]));
        m = fmaxf(m, __shfl_xor(m, 1));
        m = fmaxf(m, __shfl_xor(m, 2));
        m = fmaxf(m, __shfl_xor(m, 4));
        m = fmaxf(m, __shfl_xor(m, 8));
        m = fmaxf(m, 1e-20f);
        const int lrow = wv * 16 + kg * 4 + r;
        if (l15 == 0) scale[row0 + lrow] = m * (1.f / 127.f);
        const float inv = 127.f / m;
        #pragma unroll
        for (int nf = 0; nf < 8; ++nf) {
            const int q = (int)rintf(acc[nf][r] * inv) + 128;   // [1,255]
            As8[lrow * FD + nf * 16 + l15] = (uchar)q;
        }
    }
    __syncthreads();
    #pragma unroll
    for (int it = 0; it < 2; ++it) {
        const int o = (tid + it * 256) * 16;
        *(u32x4*)(S8 + (size_t)row0 * FD + o) = *(const u32x4*)(As8 + o);
    }
}

// ---------------------------------------------------------------------------
// Meta[e] = { edge_col[e], f32bits(edge_val[e] * scale[edge_col[e]]) }
// Interleaved so spmm reads one 8B broadcast load per edge, no readlanes.
// ---------------------------------------------------------------------------
__global__ __launch_bounds__(256) void build_meta(const int* __restrict__ ecol,
                                                  const float* __restrict__ eval_,
                                                  const float* __restrict__ scale,
                                                  u32x2* __restrict__ Meta) {
    const int i = blockIdx.x * 256 + threadIdx.x;
    if (i < NEDGES) {
        const int c = ecol[i];
        u32x2 m;
        m.x = (uint)c;
        m.y = __float_as_uint(eval_[i] * scale[c]);
        Meta[i] = m;
    }
}

// ---------------------------------------------------------------------------
// SpMM: one wave per row, TWO edges per wave-instruction.
//   h = lane&1  -> edge parity within a pair; q = lane>>1 -> feature quad.
// Per pair: 1 per-lane 8B meta load (broadcast), 1 dword gather (= 2 full
// 128B int8 rows per instr), 4 cvt_f32_ubyte + 4 fma + 1 sv add.
// 8-edge chunks (4 pairs), A/B rotation: gathers for c+1 and meta for c+2
// issued before PROCessing c. Tail validity: per-lane cndmask, LAST chunk
// only. Flush: 5x shfl_xor(1) + one float4 store per row from even lanes.
// ---------------------------------------------------------------------------
__global__ __launch_bounds__(256, 8) void spmm_pair(const int* __restrict__ rptr,
                                                    const u32x2* __restrict__ Meta,
                                                    const uchar* __restrict__ S8,
                                                    const float* __restrict__ bias,
                                                    float* __restrict__ out) {
    const int row = (blockIdx.x * 256 + threadIdx.x) >> 6;   // 100000 waves exact
    const int lane = threadIdx.x & 63;
    const int h = lane & 1;            // edge parity
    const int q = lane >> 1;           // feature quad 0..31
    const uint voff = (uint)q << 2;

    const int E0 = __builtin_amdgcn_readfirstlane(rptr[row]);
    const int E1 = __builtin_amdgcn_readfirstlane(rptr[row + 1]);
    const float4 b4 = *(const float4*)&bias[q * 4];

    float a0 = 0.f, a1 = 0.f, a2 = 0.f, a3 = 0.f, sv = 0.f;

    const int nc = (E1 - E0 + 7) >> 3;
    if (nc > 0) {

#define LOADMETA(M_, c) { \
        _Pragma("unroll") for (int pp = 0; pp < 4; ++pp) { \
            const int e_ = min(E0 + (c) * 8 + 2 * pp + h, E1 - 1); \
            M_[pp] = Meta[e_]; } }

#define GATHER(G_, M_) { \
        _Pragma("unroll") for (int pp = 0; pp < 4; ++pp) { \
            G_[pp] = *(const uint*)(S8 + ((size_t)M_[pp].x << 7) + voff); } }

#define PROC1(g_, vv_) { \
        a0 = fmaf(vv_, (float)( (g_)        & 0xffu), a0); \
        a1 = fmaf(vv_, (float)(((g_) >>  8) & 0xffu), a1); \
        a2 = fmaf(vv_, (float)(((g_) >> 16) & 0xffu), a2); \
        a3 = fmaf(vv_, (float)( (g_) >> 24        ),  a3); \
        sv += vv_; }

#define PROC(G_, M_) { \
        _Pragma("unroll") for (int pp = 0; pp < 4; ++pp) { \
            const float vv = __uint_as_float(M_[pp].y); \
            PROC1(G_[pp], vv) } }

#define PROC_TAIL(G_, M_, c) { \
        _Pragma("unroll") for (int pp = 0; pp < 4; ++pp) { \
            const int e_ = E0 + (c) * 8 + 2 * pp + h; \
            float vv = __uint_as_float(M_[pp].y); \
            vv = (e_ < E1) ? vv : 0.f; \
            PROC1(G_[pp], vv) } }

#define BODY(MC, MN, GC, GN, c) { \
        if ((c) + 1 < nc) GATHER(GN, MN); \
        if ((c) + 2 < nc) LOADMETA(MC, (c) + 2); \
        if ((c) == nc - 1) { PROC_TAIL(GC, MC##save, c) } \
        else { PROC(GC, MC##save) } }

        u32x2 mA[4], mB[4];
        uint gA[4], gB[4];

        LOADMETA(mA, 0);
        GATHER(gA, mA);
        if (nc > 1) LOADMETA(mB, 1);

        // mAsave/mBsave aliases: PROC of chunk c uses the meta that produced
        // its gathers; since LOADMETA(mA, c+2) overwrites mA while PROC(c)
        // still needs it for vv, keep a copy of the .y values.
        int c = 0;
        while (true) {
            float vvA[4];
            #pragma unroll
            for (int pp = 0; pp < 4; ++pp) vvA[pp] = __uint_as_float(mA[pp].y);
            if (c + 1 < nc) GATHER(gB, mB);
            if (c + 2 < nc) LOADMETA(mA, c + 2);
            if (c == nc - 1) {
                #pragma unroll
                for (int pp = 0; pp < 4; ++pp) {
                    const int e_ = E0 + c * 8 + 2 * pp + h;
                    const float vv = (e_ < E1) ? vvA[pp] : 0.f;
                    PROC1(gA[pp], vv)
                }
            } else {
                #pragma unroll
                for (int pp = 0; pp < 4; ++pp) PROC1(gA[pp], vvA[pp])
            }
            if (++c >= nc) break;

            float vvB[4];
            #pragma unroll
            for (int pp = 0; pp < 4; ++pp) vvB[pp] = __uint_as_float(mB[pp].y);
            if (c + 1 < nc) GATHER(gA, mA);
            if (c + 2 < nc) LOADMETA(mB, c + 2);
            if (c == nc - 1) {
                #pragma unroll
                for (int pp = 0; pp < 4; ++pp) {
                    const int e_ = E0 + c * 8 + 2 * pp + h;
                    const float vv = (e_ < E1) ? vvB[pp] : 0.f;
                    PROC1(gB[pp], vv)
                }
            } else {
                #pragma unroll
                for (int pp = 0; pp < 4; ++pp) PROC1(gB[pp], vvB[pp])
            }
            if (++c >= nc) break;
        }
#undef BODY
#undef PROC_TAIL
#undef PROC
#undef PROC1
#undef GATHER
#undef LOADMETA
    }

    // cross-parity reduce (lane 2k <-> 2k+1) and store from even lanes
    a0 += __shfl_xor(a0, 1);
    a1 += __shfl_xor(a1, 1);
    a2 += __shfl_xor(a2, 1);
    a3 += __shfl_xor(a3, 1);
    sv += __shfl_xor(sv, 1);

    if (h == 0) {
        float4 o;
        o.x = fmaf(-128.f, sv, a0) + b4.x;
        o.y = fmaf(-128.f, sv, a1) + b4.y;
        o.z = fmaf(-128.f, sv, a2) + b4.z;
        o.w = fmaf(-128.f, sv, a3) + b4.w;
        *(float4*)&out[(size_t)row * FD + (q << 2)] = o;
    }
}

// ---------------------------------------------------------------------------
extern "C" void kernel_launch(void* const* d_in, const int* in_sizes, int n_in,
                              void* d_out, int out_size, void* d_ws, size_t ws_size,
                              hipStream_t stream) {
    const float* X    = (const float*)d_in[0];
    const int*   erow = (const int*)d_in[1];
    const int*   ecol = (const int*)d_in[2];
    const float* eval_= (const float*)d_in[3];
    const float* W    = (const float*)d_in[4];
    const float* bias = (const float*)d_in[5];
    float* out = (float*)d_out;

    uchar* S8    = (uchar*)d_ws;                               // 12.8 MB
    float* scale = (float*)((char*)d_ws + 13u * 1024 * 1024);  // 400 KB
    int*   rpt   = (int*)((char*)d_ws + 14u * 1024 * 1024);    // 400 KB
    u32x2* Meta  = (u32x2*)((char*)d_ws + 15u * 1024 * 1024);  // 12.8 MB
    ushort* Wt   = (ushort*)((char*)d_ws + 28u * 1024 * 1024); // 32 KB

    prep<<<16 + (NNODES + 256) / 256, 256, 0, stream>>>(W, Wt, erow, rpt);
    gemm_mfma_q8<<<NPAD / BM, 256, 0, stream>>>(X, Wt, S8, scale);
    build_meta<<<(NEDGES + 255) / 256, 256, 0, stream>>>(ecol, eval_, scale, Meta);
    spmm_pair<<<NNODES / 4, 256, 0, stream>>>(rpt, Meta, S8, bias, out);
}

// Round 9
// 97.085 us; speedup vs baseline: 1.8170x; 1.8170x over previous
//
#include <hip/hip_runtime.h>

typedef unsigned int uint;
typedef unsigned short ushort;
typedef unsigned char uchar;
typedef unsigned long long ull;
typedef __attribute__((ext_vector_type(4))) float f32x4;
typedef __attribute__((ext_vector_type(2))) float f32x2;
typedef __attribute__((ext_vector_type(4))) uint u32x4;
typedef __attribute__((ext_vector_type(2))) uint u32x2;

#define NNODES 100000
#define NPAD   100032
#define NEDGES 1600000
#define FD 128
#define BM 64
#define RPW 8                  // rows per spmm wave -> 12500 waves, 3125 blocks

__device__ __forceinline__ uint cvt_pk_bf16(float lo, float hi) {
    uint r;
    asm("v_cvt_pk_bf16_f32 %0, %1, %2" : "=v"(r) : "v"(lo), "v"(hi));
    return r;
}
__device__ __forceinline__ int swz(int row, int k) {
    return (row * 256 + k * 2) ^ ((row & 7) << 4);
}

// ---------------------------------------------------------------------------
// prep: blocks 0-15 build Wt (bf16(W^T), pre-swizzled); blocks 16+ build
// row_ptr[r] = lower_bound(edge_row, r).
// ---------------------------------------------------------------------------
__global__ __launch_bounds__(256) void prep(const float* __restrict__ W,
                                            ushort* __restrict__ Wt,
                                            const int* __restrict__ rows,
                                            int* __restrict__ ptr) {
    const int bid = blockIdx.x;
    if (bid < 16) {
        const int sid = bid * 256 + threadIdx.x;   // 4096 slots
        const int n = sid & 127, k0 = (sid >> 7) * 4;
        const float w0 = W[(k0 + 0) * FD + n];
        const float w1 = W[(k0 + 1) * FD + n];
        const float w2 = W[(k0 + 2) * FD + n];
        const float w3 = W[(k0 + 3) * FD + n];
        u32x2 p;
        p.x = cvt_pk_bf16(w0, w1);
        p.y = cvt_pk_bf16(w2, w3);
        *(u32x2*)((char*)Wt + swz(n, k0)) = p;
    } else {
        const int r = (bid - 16) * 256 + threadIdx.x;
        if (r > NNODES) return;
        int lo = 0, hi = NEDGES;
        while (lo < hi) {
            const int mid = (lo + hi) >> 1;
            const bool lt = rows[mid] < r;
            lo = lt ? mid + 1 : lo;
            hi = lt ? hi : mid;
        }
        ptr[r] = lo;
    }
}

// ---------------------------------------------------------------------------
// GEMM: S = X @ W via bf16 MFMA + per-row symmetric int8 quant (biased u8).
// ---------------------------------------------------------------------------
__global__ __launch_bounds__(256) void gemm_mfma_q8(const float* __restrict__ X,
                                                    const ushort* __restrict__ Wt,
                                                    uchar* __restrict__ S8,
                                                    float* __restrict__ scale) {
    __shared__ ushort As[BM * FD];   // 16 KB, swizzled; reused as u8 in epilogue
    __shared__ ushort Bs[FD * FD];   // 32 KB, swizzled
    const int tid = threadIdx.x;
    const int row0 = blockIdx.x * BM;

    #pragma unroll
    for (int it = 0; it < 8; ++it) {
        const int idx = tid + it * 256;
        const int r = idx >> 5, k0 = (idx & 31) * 4;
        const int grow = min(row0 + r, NNODES - 1);
        const float4 g = *(const float4*)&X[grow * FD + k0];
        u32x2 p;
        p.x = cvt_pk_bf16(g.x, g.y);
        p.y = cvt_pk_bf16(g.z, g.w);
        *(u32x2*)((char*)As + swz(r, k0)) = p;
    }
    #pragma unroll
    for (int it = 0; it < 8; ++it) {
        const int b = (tid + it * 256) * 16;
        *(u32x4*)((char*)Bs + b) = *(const u32x4*)((const char*)Wt + b);
    }
    __syncthreads();

    const int lane = tid & 63, wv = tid >> 6;
    const int l15 = lane & 15, kg = lane >> 4;
    const int arow = wv * 16 + l15;

    f32x4 acc[8];
    #pragma unroll
    for (int i = 0; i < 8; ++i) acc[i] = (f32x4)0.f;

    #pragma unroll
    for (int ks = 0; ks < 4; ++ks) {
        const int k0 = ks * 32 + kg * 8;
        const u32x4 a = *(const u32x4*)((const char*)As + swz(arow, k0));
        #pragma unroll
        for (int nf = 0; nf < 8; ++nf) {
            const u32x4 b = *(const u32x4*)((const char*)Bs + swz(nf * 16 + l15, k0));
            asm volatile("v_mfma_f32_16x16x32_bf16 %0, %1, %2, %0"
                         : "+v"(acc[nf]) : "v"(a), "v"(b));
        }
    }
    asm volatile("s_nop 7\ns_nop 7\ns_nop 7");

    __syncthreads();
    uchar* As8 = (uchar*)As;

    #pragma unroll
    for (int r = 0; r < 4; ++r) {
        float m = 0.f;
        #pragma unroll
        for (int nf = 0; nf < 8; ++nf) m = fmaxf(m, fabsf(acc[nf][r]));
        m = fmaxf(m, __shfl_xor(m, 1));
        m = fmaxf(m, __shfl_xor(m, 2));
        m = fmaxf(m, __shfl_xor(m, 4));
        m = fmaxf(m, __shfl_xor(m, 8));
        m = fmaxf(m, 1e-20f);
        const int lrow = wv * 16 + kg * 4 + r;
        if (l15 == 0) scale[row0 + lrow] = m * (1.f / 127.f);
        const float inv = 127.f / m;
        #pragma unroll
        for (int nf = 0; nf < 8; ++nf) {
            const int q = (int)rintf(acc[nf][r] * inv) + 128;   // [1,255]
            As8[lrow * FD + nf * 16 + l15] = (uchar)q;
        }
    }
    __syncthreads();
    #pragma unroll
    for (int it = 0; it < 2; ++it) {
        const int o = (tid + it * 256) * 16;
        *(u32x4*)(S8 + (size_t)row0 * FD + o) = *(const u32x4*)(As8 + o);
    }
}

// ---------------------------------------------------------------------------
// VS[e] = edge_val[e] * scale[edge_col[e]]
// ---------------------------------------------------------------------------
__global__ __launch_bounds__(256) void build_vs(const int* __restrict__ ecol,
                                                const float* __restrict__ eval_,
                                                const float* __restrict__ scale,
                                                float* __restrict__ VS) {
    const int i = blockIdx.x * 256 + threadIdx.x;
    if (i < NEDGES) VS[i] = eval_[i] * scale[ecol[i]];
}

// ---------------------------------------------------------------------------
// SpMM: wave owns RPW=8 rows = one contiguous edge range. 16-edge batches:
// ONE combined nontemporal dword meta load per batch (lanes 0-15 cols,
// 16-31 VS, 32-47 rows). Gathers 1 batch ahead (16 ushort gathers = full
// 128B int8 rows in flight), meta rotates through 3 buffers (2 batches
// slack). Row/val extracted just-in-time via readlane (SGPR); row-change
// flush is a uniform scalar branch; ALL stores full-wave nontemporal.
// ---------------------------------------------------------------------------
__global__ __launch_bounds__(256, 8) void spmm16(const int* __restrict__ rptr,
                                                 const int* __restrict__ erow,
                                                 const int* __restrict__ ecol,
                                                 const float* __restrict__ VS,
                                                 const uchar* __restrict__ S8,
                                                 const float* __restrict__ bias,
                                                 float* __restrict__ out) {
    const int wv = (blockIdx.x * 256 + threadIdx.x) >> 6;   // 12500 waves exact
    const int lane = threadIdx.x & 63;
    const int r0 = wv * RPW;
    const f32x2 b2 = *(const f32x2*)&bias[lane * 2];
    const uint voff = (uint)lane << 1;

    const int E0 = __builtin_amdgcn_readfirstlane(rptr[r0]);
    const int E1 = __builtin_amdgcn_readfirstlane(rptr[r0 + RPW]);

    // combined meta pointer: lanes 0-15 cols, 16-31 VS, 32-47 rows (48-63 dup)
    const int ml = lane & 15;
    const uint* mb = (lane < 16) ? (const uint*)ecol
                   : (lane < 32) ? (const uint*)VS
                                 : (const uint*)erow;

    float a0 = 0.f, a1 = 0.f, sv = 0.f;

    if (E0 < E1) {
        const int nb = (E1 - E0 + 15) >> 4;
        int rcur = __builtin_amdgcn_readfirstlane(erow[E0]);

#define LOADMETA(M_, b_) { \
        const int i_ = min(E0 + (b_) * 16 + ml, NEDGES - 1); \
        M_ = __builtin_nontemporal_load(&mb[i_]); }

#define GATHER(G_, M_) { \
        _Pragma("unroll") for (int j = 0; j < 16; ++j) { \
            const uint c_ = (uint)__builtin_amdgcn_readlane((int)(M_), j); \
            G_[j] = (uint)*(const ushort*)(S8 + ((size_t)c_ << 7) + voff); } }

#define FLUSH() { f32x2 o_; \
        o_.x = fmaf(-128.f, sv, a0) + b2.x; \
        o_.y = fmaf(-128.f, sv, a1) + b2.y; \
        __builtin_nontemporal_store(o_, (f32x2*)&out[(size_t)rcur * FD + voff]); \
        a0 = 0.f; a1 = 0.f; sv = 0.f; }

#define EDGE(gj, M_, j) { \
        const int rj = __builtin_amdgcn_readlane((int)(M_), 32 + j); \
        const float vj = __int_as_float(__builtin_amdgcn_readlane((int)(M_), 16 + j)); \
        if (rj != rcur) { FLUSH(); rcur = rj; } \
        a0 = fmaf(vj, (float)(gj & 0xffu), a0); \
        a1 = fmaf(vj, (float)(gj >> 8), a1); \
        sv += vj; }

#define PROC(G_, M_) { \
        _Pragma("unroll") for (int j = 0; j < 16; ++j) { EDGE(G_[j], M_, j) } }

#define PROC_LAST(G_, M_, b_) { \
        _Pragma("unroll") for (int j = 0; j < 16; ++j) { \
            if (E0 + (b_) * 16 + j < E1) { EDGE(G_[j], M_, j) } } }

// STEP: PROC batch b (gathers GC, meta MC); prefetch gathers for b+1 (GN
// from MN) and meta for b+2 (into ML).
#define STEP(GC, GN, MC, MN, ML, b_) { \
        if ((b_) + 1 < nb) GATHER(GN, MN); \
        if ((b_) + 2 < nb) LOADMETA(ML, (b_) + 2); \
        if ((b_) == nb - 1) { PROC_LAST(GC, MC, b_) } else { PROC(GC, MC) } }

        uint mA, mB = 0, mC = 0;
        uint gA[16], gB[16];

        LOADMETA(mA, 0);
        LOADMETA(mB, 1);          // clamped if nb==1; never consumed then
        GATHER(gA, mA);

        int b = 0;
        while (true) {            // period 6 = lcm(gather 2, meta 3)
            STEP(gA, gB, mA, mB, mC, b); if (++b >= nb) break;
            STEP(gB, gA, mB, mC, mA, b); if (++b >= nb) break;
            STEP(gA, gB, mC, mA, mB, b); if (++b >= nb) break;
            STEP(gB, gA, mA, mB, mC, b); if (++b >= nb) break;
            STEP(gA, gB, mB, mC, mA, b); if (++b >= nb) break;
            STEP(gB, gA, mC, mA, mB, b); if (++b >= nb) break;
        }
        FLUSH();

#undef STEP
#undef PROC_LAST
#undef PROC
#undef EDGE
#undef FLUSH
#undef GATHER
#undef LOADMETA
    }

    // bias-only output for empty rows (rare but must be correct)
    const int rl = r0 + ((lane < RPW) ? lane : RPW - 1);
    const bool em = (lane < RPW) && (rptr[rl] == rptr[rl + 1]);
    ull mask = __ballot(em);
    while (mask) {
        const int i = __ffsll(mask) - 1;
        mask &= mask - 1;
        __builtin_nontemporal_store(b2, (f32x2*)&out[(size_t)(r0 + i) * FD + voff]);
    }
}

// ---------------------------------------------------------------------------
extern "C" void kernel_launch(void* const* d_in, const int* in_sizes, int n_in,
                              void* d_out, int out_size, void* d_ws, size_t ws_size,
                              hipStream_t stream) {
    const float* X    = (const float*)d_in[0];
    const int*   erow = (const int*)d_in[1];
    const int*   ecol = (const int*)d_in[2];
    const float* eval_= (const float*)d_in[3];
    const float* W    = (const float*)d_in[4];
    const float* bias = (const float*)d_in[5];
    float* out = (float*)d_out;

    uchar* S8    = (uchar*)d_ws;                               // 12.8 MB
    float* scale = (float*)((char*)d_ws + 13u * 1024 * 1024);  // 400 KB
    int*   rpt   = (int*)((char*)d_ws + 14u * 1024 * 1024);    // 400 KB
    float* VS    = (float*)((char*)d_ws + 15u * 1024 * 1024);  // 6.4 MB
    ushort* Wt   = (ushort*)((char*)d_ws + 22u * 1024 * 1024); // 32 KB

    prep<<<16 + (NNODES + 256) / 256, 256, 0, stream>>>(W, Wt, erow, rpt);
    gemm_mfma_q8<<<NPAD / BM, 256, 0, stream>>>(X, Wt, S8, scale);
    build_vs<<<(NEDGES + 255) / 256, 256, 0, stream>>>(ecol, eval_, scale, VS);
    spmm16<<<NNODES / RPW / 4, 256, 0, stream>>>(rpt, erow, ecol, VS, S8, bias, out);
}

// Round 10
// 86.955 us; speedup vs baseline: 2.0287x; 1.1165x over previous
//
#include <hip/hip_runtime.h>

typedef unsigned int uint;
typedef unsigned short ushort;
typedef unsigned char uchar;
typedef unsigned long long ull;
typedef __attribute__((ext_vector_type(4))) float f32x4;
typedef __attribute__((ext_vector_type(4))) uint u32x4;
typedef __attribute__((ext_vector_type(2))) uint u32x2;

#define NNODES 100000
#define NPAD   100032
#define NEDGES 1600000
#define FD 128
#define BM 64
#define RPW 10                 // rows per spmm wave; 10000 waves, 2500 blocks

__device__ __forceinline__ uint cvt_pk_bf16(float lo, float hi) {
    uint r;
    asm("v_cvt_pk_bf16_f32 %0, %1, %2" : "=v"(r) : "v"(lo), "v"(hi));
    return r;
}
__device__ __forceinline__ int swz(int row, int k) {
    return (row * 256 + k * 2) ^ ((row & 7) << 4);
}

// ---------------------------------------------------------------------------
// prep: blocks 0-15 build Wt (bf16(W^T), pre-swizzled); blocks 16+ build
// row_ptr[r] = lower_bound(edge_row, r).
// ---------------------------------------------------------------------------
__global__ __launch_bounds__(256) void prep(const float* __restrict__ W,
                                            ushort* __restrict__ Wt,
                                            const int* __restrict__ rows,
                                            int* __restrict__ ptr) {
    const int bid = blockIdx.x;
    if (bid < 16) {
        const int sid = bid * 256 + threadIdx.x;   // 4096 slots
        const int n = sid & 127, k0 = (sid >> 7) * 4;
        const float w0 = W[(k0 + 0) * FD + n];
        const float w1 = W[(k0 + 1) * FD + n];
        const float w2 = W[(k0 + 2) * FD + n];
        const float w3 = W[(k0 + 3) * FD + n];
        u32x2 p;
        p.x = cvt_pk_bf16(w0, w1);
        p.y = cvt_pk_bf16(w2, w3);
        *(u32x2*)((char*)Wt + swz(n, k0)) = p;
    } else {
        const int r = (bid - 16) * 256 + threadIdx.x;
        if (r > NNODES) return;
        int lo = 0, hi = NEDGES;
        while (lo < hi) {
            const int mid = (lo + hi) >> 1;
            const bool lt = rows[mid] < r;
            lo = lt ? mid + 1 : lo;
            hi = lt ? hi : mid;
        }
        ptr[r] = lo;
    }
}

// ---------------------------------------------------------------------------
// GEMM: S = X @ W via bf16 MFMA + per-row symmetric int8 quant (biased u8).
// ---------------------------------------------------------------------------
__global__ __launch_bounds__(256) void gemm_mfma_q8(const float* __restrict__ X,
                                                    const ushort* __restrict__ Wt,
                                                    uchar* __restrict__ S8,
                                                    float* __restrict__ scale) {
    __shared__ ushort As[BM * FD];   // 16 KB, swizzled; reused as u8 in epilogue
    __shared__ ushort Bs[FD * FD];   // 32 KB, swizzled
    const int tid = threadIdx.x;
    const int row0 = blockIdx.x * BM;

    #pragma unroll
    for (int it = 0; it < 8; ++it) {
        const int idx = tid + it * 256;
        const int r = idx >> 5, k0 = (idx & 31) * 4;
        const int grow = min(row0 + r, NNODES - 1);
        const float4 g = *(const float4*)&X[grow * FD + k0];
        u32x2 p;
        p.x = cvt_pk_bf16(g.x, g.y);
        p.y = cvt_pk_bf16(g.z, g.w);
        *(u32x2*)((char*)As + swz(r, k0)) = p;
    }
    #pragma unroll
    for (int it = 0; it < 8; ++it) {
        const int b = (tid + it * 256) * 16;
        *(u32x4*)((char*)Bs + b) = *(const u32x4*)((const char*)Wt + b);
    }
    __syncthreads();

    const int lane = tid & 63, wv = tid >> 6;
    const int l15 = lane & 15, kg = lane >> 4;
    const int arow = wv * 16 + l15;

    f32x4 acc[8];
    #pragma unroll
    for (int i = 0; i < 8; ++i) acc[i] = (f32x4)0.f;

    #pragma unroll
    for (int ks = 0; ks < 4; ++ks) {
        const int k0 = ks * 32 + kg * 8;
        const u32x4 a = *(const u32x4*)((const char*)As + swz(arow, k0));
        #pragma unroll
        for (int nf = 0; nf < 8; ++nf) {
            const u32x4 b = *(const u32x4*)((const char*)Bs + swz(nf * 16 + l15, k0));
            asm volatile("v_mfma_f32_16x16x32_bf16 %0, %1, %2, %0"
                         : "+v"(acc[nf]) : "v"(a), "v"(b));
        }
    }
    asm volatile("s_nop 7\ns_nop 7\ns_nop 7");

    __syncthreads();
    uchar* As8 = (uchar*)As;

    #pragma unroll
    for (int r = 0; r < 4; ++r) {
        float m = 0.f;
        #pragma unroll
        for (int nf = 0; nf < 8; ++nf) m = fmaxf(m, fabsf(acc[nf][r]));
        m = fmaxf(m, __shfl_xor(m, 1));
        m = fmaxf(m, __shfl_xor(m, 2));
        m = fmaxf(m, __shfl_xor(m, 4));
        m = fmaxf(m, __shfl_xor(m, 8));
        m = fmaxf(m, 1e-20f);
        const int lrow = wv * 16 + kg * 4 + r;
        if (l15 == 0) scale[row0 + lrow] = m * (1.f / 127.f);
        const float inv = 127.f / m;
        #pragma unroll
        for (int nf = 0; nf < 8; ++nf) {
            const int q = (int)rintf(acc[nf][r] * inv) + 128;   // [1,255]
            As8[lrow * FD + nf * 16 + l15] = (uchar)q;
        }
    }
    __syncthreads();
    #pragma unroll
    for (int it = 0; it < 2; ++it) {
        const int o = (tid + it * 256) * 16;
        *(u32x4*)(S8 + (size_t)row0 * FD + o) = *(const u32x4*)(As8 + o);
    }
}

// ---------------------------------------------------------------------------
// VS[e] = edge_val[e] * scale[edge_col[e]]
// ---------------------------------------------------------------------------
__global__ __launch_bounds__(256) void build_vs(const int* __restrict__ ecol,
                                                const float* __restrict__ eval_,
                                                const float* __restrict__ scale,
                                                float* __restrict__ VS) {
    const int i = blockIdx.x * 256 + threadIdx.x;
    if (i < NEDGES) VS[i] = eval_[i] * scale[ecol[i]];
}

// ---------------------------------------------------------------------------
// SpMM (r6 structure + uniform-batch fast path). Wave owns RPW=10 rows =
// one contiguous edge range. Per 8-edge batch: ONE combined meta load
// (lanes 0-7 cols, 8-15 VS, 16-23 rows). Gathers issued 1 batch ahead,
// meta loaded 3 ahead through a 3-buffer rotation (meta stays LIVE through
// its PROC so divergent batches can readlane rows just-in-time). Upfront
// extraction per batch: 8 vs + rfirst + rlast. If rfirst==rlast (uniform
// batch, ~50%), skip ALL per-edge row logic: at most one flush at batch
// start, then 8 unconditional accumulates.
// ---------------------------------------------------------------------------
__global__ __launch_bounds__(256, 8) void spmm_u(const int* __restrict__ rptr,
                                                 const int* __restrict__ erow,
                                                 const int* __restrict__ ecol,
                                                 const float* __restrict__ VS,
                                                 const uchar* __restrict__ S8,
                                                 const float* __restrict__ bias,
                                                 float* __restrict__ out) {
    const int wv = (blockIdx.x * 256 + threadIdx.x) >> 6;   // 10000 waves exact
    const int lane = threadIdx.x & 63;
    const int r0 = wv * RPW;
    const float2 b2 = *(const float2*)&bias[lane * 2];
    const uint voff = (uint)lane << 1;

    const int E0 = __builtin_amdgcn_readfirstlane(rptr[r0]);
    const int E1 = __builtin_amdgcn_readfirstlane(rptr[r0 + RPW]);

    const int sl = lane & 7;
    const uint* mb = (lane < 8) ? (const uint*)ecol
                   : (lane < 16) ? (const uint*)VS
                                 : (const uint*)erow;

    float a0 = 0.f, a1 = 0.f, sv = 0.f;

    if (E0 < E1) {
        const int nb = (E1 - E0 + 7) >> 3;
        int rcur = __builtin_amdgcn_readfirstlane(erow[E0]);

#define LOADMETA(M_, b_) { \
        const int i_ = min(E0 + (b_) * 8 + sl, NEDGES - 1); \
        M_ = mb[i_]; }

#define GATHER(G_, M_) { \
        _Pragma("unroll") for (int j = 0; j < 8; ++j) { \
            const uint c_ = (uint)__builtin_amdgcn_readlane((int)(M_), j); \
            G_[j] = (uint)*(const ushort*)(S8 + ((size_t)c_ << 7) + voff); } }

#define EXTRACT(V_, RF_, RL_, M_) { \
        _Pragma("unroll") for (int j = 0; j < 8; ++j) \
            V_[j] = __int_as_float(__builtin_amdgcn_readlane((int)(M_), 8 + j)); \
        RF_ = __builtin_amdgcn_readlane((int)(M_), 16); \
        RL_ = __builtin_amdgcn_readlane((int)(M_), 23); }

#define FLUSH() { float2 o_; \
        o_.x = fmaf(-128.f, sv, a0) + b2.x; \
        o_.y = fmaf(-128.f, sv, a1) + b2.y; \
        *(float2*)&out[(size_t)rcur * FD + voff] = o_; \
        a0 = 0.f; a1 = 0.f; sv = 0.f; }

#define ACC(gj, vj) { \
        a0 = fmaf(vj, (float)(gj & 0xffu), a0); \
        a1 = fmaf(vj, (float)(gj >> 8), a1); \
        sv += vj; }

#define PROC(G_, V_, RF_, RL_, M_) { \
        if (RF_ == RL_) {                       /* uniform batch (scalar) */ \
            if (RF_ != rcur) { FLUSH(); rcur = RF_; } \
            _Pragma("unroll") for (int j = 0; j < 8; ++j) ACC(G_[j], V_[j]) \
        } else {                                /* divergent: JIT rows */ \
            _Pragma("unroll") for (int j = 0; j < 8; ++j) { \
                const int rj = (j == 0) ? RF_ : (j == 7) ? RL_ \
                    : __builtin_amdgcn_readlane((int)(M_), 16 + j); \
                if (rj != rcur) { FLUSH(); rcur = rj; } \
                ACC(G_[j], V_[j]) \
            } \
        } }

#define PROC_TAIL(G_, V_, RF_, RL_, M_, b_) { \
        _Pragma("unroll") for (int j = 0; j < 8; ++j) { \
            if (E0 + (b_) * 8 + j < E1) { \
                const int rj = (j == 0) ? RF_ \
                    : __builtin_amdgcn_readlane((int)(M_), 16 + j); \
                if (rj != rcur) { FLUSH(); rcur = rj; } \
                ACC(G_[j], V_[j]) \
            } } }

// STEP: gather+extract batch b+1 (from MN, kept live); PROC batch b (MC
// live for JIT rows); then refill MC with batch b+3's meta.
#define STEP(GC, GN, VC, VN, RFC, RLC, RFN, RLN, MC, MN, b_) { \
        if ((b_) + 1 < nb) { GATHER(GN, MN); EXTRACT(VN, RFN, RLN, MN); } \
        if ((b_) == nb - 1) { PROC_TAIL(GC, VC, RFC, RLC, MC, b_) } \
        else { PROC(GC, VC, RFC, RLC, MC) } \
        if ((b_) + 3 < nb) LOADMETA(MC, (b_) + 3); }

        uint mA, mB = 0, mC = 0;
        uint gA[8], gB[8];
        float vA[8], vB[8];
        int rfA = 0, rlA = 0, rfB = 0, rlB = 0;

        LOADMETA(mA, 0);
        if (nb > 1) LOADMETA(mB, 1);
        if (nb > 2) LOADMETA(mC, 2);
        GATHER(gA, mA);
        EXTRACT(vA, rfA, rlA, mA);

        int b = 0;
        while (true) {            // period 6 = lcm(meta 3, gather/extract 2)
            STEP(gA, gB, vA, vB, rfA, rlA, rfB, rlB, mA, mB, b); if (++b >= nb) break;
            STEP(gB, gA, vB, vA, rfB, rlB, rfA, rlA, mB, mC, b); if (++b >= nb) break;
            STEP(gA, gB, vA, vB, rfA, rlA, rfB, rlB, mC, mA, b); if (++b >= nb) break;
            STEP(gB, gA, vB, vA, rfB, rlB, rfA, rlA, mA, mB, b); if (++b >= nb) break;
            STEP(gA, gB, vA, vB, rfA, rlA, rfB, rlB, mB, mC, b); if (++b >= nb) break;
            STEP(gB, gA, vB, vA, rfB, rlB, rfA, rlA, mC, mA, b); if (++b >= nb) break;
        }
        FLUSH();

#undef STEP
#undef PROC_TAIL
#undef PROC
#undef ACC
#undef FLUSH
#undef EXTRACT
#undef GATHER
#undef LOADMETA
    }

    // bias-only output for empty rows (rare but must be correct)
    const int rl_ = r0 + ((lane < RPW) ? lane : RPW - 1);
    const bool em = (lane < RPW) && (rptr[rl_] == rptr[rl_ + 1]);
    ull mask = __ballot(em);
    while (mask) {
        const int i = __ffsll(mask) - 1;
        mask &= mask - 1;
        *(float2*)&out[(size_t)(r0 + i) * FD + voff] = b2;
    }
}

// ---------------------------------------------------------------------------
extern "C" void kernel_launch(void* const* d_in, const int* in_sizes, int n_in,
                              void* d_out, int out_size, void* d_ws, size_t ws_size,
                              hipStream_t stream) {
    const float* X    = (const float*)d_in[0];
    const int*   erow = (const int*)d_in[1];
    const int*   ecol = (const int*)d_in[2];
    const float* eval_= (const float*)d_in[3];
    const float* W    = (const float*)d_in[4];
    const float* bias = (const float*)d_in[5];
    float* out = (float*)d_out;

    uchar* S8    = (uchar*)d_ws;                               // 12.8 MB
    float* scale = (float*)((char*)d_ws + 13u * 1024 * 1024);  // 400 KB
    int*   rpt   = (int*)((char*)d_ws + 14u * 1024 * 1024);    // 400 KB
    float* VS    = (float*)((char*)d_ws + 15u * 1024 * 1024);  // 6.4 MB
    ushort* Wt   = (ushort*)((char*)d_ws + 22u * 1024 * 1024); // 32 KB

    prep<<<16 + (NNODES + 256) / 256, 256, 0, stream>>>(W, Wt, erow, rpt);
    gemm_mfma_q8<<<NPAD / BM, 256, 0, stream>>>(X, Wt, S8, scale);
    build_vs<<<(NEDGES + 255) / 256, 256, 0, stream>>>(ecol, eval_, scale, VS);
    spmm_u<<<NNODES / RPW / 4, 256, 0, stream>>>(rpt, erow, ecol, VS, S8, bias, out);
}